// Round 7
// baseline (1514.350 us; speedup 1.0000x reference)
//
#include <hip/hip_runtime.h>
#include <hip/hip_bf16.h>

typedef unsigned int u32;
typedef unsigned long long u64;

#define HH 384
#define WW 768
#define HW (HH*WW)
#define H4 96
#define W4 192
#define DLR 32
#define DHR 128
#define TOPK 8000
#define NTH 256
#define NBLK (HW/NTH)    // 1152
#define NCHUNK 1152
#define SGRID 1024

// k_prob tiling: 4 rows x 64 cols per block
#define PTW 18
#define PTH 3

struct SelState {
    u32 K, all_pass, prefix, r, cutoff, n_take, need_rank;
};

// ---- compile-time D-interp tables (bit-identical weights to runtime formula) ----
struct DTab {
    float A[32];      // sum coefficients:  sum  = sum_k A[k]*S[k]
    float B[32];      // sumd coefficients: sumd = sum_k B[k]*S[k]
    int   f[32];      // first d with lo==k (-1 if none)
    int   l[32];      // last d with lo==k
    float w[128];     // w per sample d
};
constexpr DTab mk_dtab(){
    DTab t{};
    const float CD = (float)(31.0/127.0);
    for (int k = 0; k < 32; ++k){ t.A[k]=0.f; t.B[k]=0.f; t.f[k]=-1; t.l[k]=-1; }
    for (int d = 0; d < 128; ++d){
        float pos = (float)d * CD;
        int lo = (int)pos; if (lo > 31) lo = 31;
        int hi = (lo+1 > 31) ? 31 : lo+1;
        float w = pos - (float)lo;
        t.w[d] = w;
        t.A[lo] += 1.0f - w;            t.A[hi] += w;
        t.B[lo] += (float)d*(1.0f - w); t.B[hi] += (float)d*w;
        if (t.f[lo] < 0) t.f[lo] = d;
        t.l[lo] = d;
    }
    return t;
}
static constexpr DTab DT = mk_dtab();

// =============== k_prob: interp + prob stats + confidence ===============
__global__ __launch_bounds__(NTH) void k_prob(const float* __restrict__ P,
        const float* __restrict__ edge, const float* __restrict__ occ,
        float* __restrict__ conf, float* __restrict__ disp0, u32* __restrict__ dhk,
        u32* __restrict__ hist, u32* __restrict__ barcnt, SelState* st){
    // fold init: zero histograms + state (before any use; consumed by later kernels)
    int gtid = blockIdx.x*NTH + threadIdx.x;
    if (gtid < 2*65536) hist[gtid] = 0u;
    if (gtid == 0){
        *barcnt = 0u;
        st->K=0; st->all_pass=0; st->prefix=0; st->r=TOPK; st->cutoff=0; st->n_take=0; st->need_rank=0;
    }

    __shared__ float Sl[DLR][PTH][PTW];     // 6912 B
    __shared__ float YL[4][DLR][19];        // 9728 B (pad 19 for banks)

    int bx = blockIdx.x % 12, by = blockIdx.x / 12;
    int X = bx*64, Y = by*4;
    const float CY = (float)(95.0/383.0);
    const float CX = (float)(191.0/767.0);

    float fy0 = (float)Y * CY; int y0min = (int)fy0; if (y0min > H4-1) y0min = H4-1;
    float fx0 = (float)X * CX; int x0min = (int)fx0; if (x0min > W4-1) x0min = W4-1;

    // stage P_lr window (coalesced global, conflict-free LDS)
    for (int e = threadIdx.x; e < DLR*PTH*PTW; e += NTH){
        int dl  = e / (PTH*PTW);
        int rem = e % (PTH*PTW);
        int ry  = rem / PTW;
        int cx  = rem % PTW;
        int gy = min(y0min + ry, H4-1);
        int gx = min(x0min + cx, W4-1);
        ((float*)Sl)[e] = P[dl*(H4*W4) + gy*W4 + gx];
    }
    __syncthreads();

    // shared y-lerp: 4 out-rows x 32 planes x 18 cols
    for (int e = threadIdx.x; e < 4*DLR*18; e += NTH){
        int ly  = e / (DLR*18);
        int rem = e % (DLR*18);
        int dl  = rem / 18;
        int cx  = rem % 18;
        float fy = (float)(Y + ly) * CY;
        int y0 = (int)fy; if (y0 > H4-1) y0 = H4-1;
        int y1 = min(y0+1, H4-1);
        float wy = fy - (float)y0;
        int ry = y0 - y0min, ryb = y1 - y0min;
        YL[ly][dl][cx] = Sl[dl][ry][cx]*(1.0f-wy) + Sl[dl][ryb][cx]*wy;
    }
    __syncthreads();

    int lx = threadIdx.x & 63, ly = threadIdx.x >> 6;
    int x = X + lx, y = Y + ly;
    int idx = y*WW + x;

    float fx = (float)x * CX;
    int x0 = (int)fx; if (x0 > W4-1) x0 = W4-1;
    float wx = fx - (float)x0;
    float omwx = 1.0f - wx;
    int cxl = x0 - x0min;           // 0..16

    float S[DLR];
    #pragma unroll
    for (int k = 0; k < DLR; ++k)
        S[k] = YL[ly][k][cxl]*omwx + YL[ly][k][cxl+1]*wx;

    // sum / sumd via constexpr coefficients, 4 independent chains
    float s0=0.f,s1=0.f,s2=0.f,s3=0.f, u0=0.f,u1=0.f,u2=0.f,u3=0.f;
    #pragma unroll
    for (int k = 0; k < DLR; k += 4){
        s0 = fmaf(DT.A[k  ], S[k  ], s0); u0 = fmaf(DT.B[k  ], S[k  ], u0);
        s1 = fmaf(DT.A[k+1], S[k+1], s1); u1 = fmaf(DT.B[k+1], S[k+1], u1);
        s2 = fmaf(DT.A[k+2], S[k+2], s2); u2 = fmaf(DT.B[k+2], S[k+2], u2);
        s3 = fmaf(DT.A[k+3], S[k+3], s3); u3 = fmaf(DT.B[k+3], S[k+3], u3);
    }
    float sum  = (s0+s1) + (s2+s3);
    float sumd = (u0+u1) + (u2+u3);

    // top-2 + argmax via per-segment monotonicity (candidate values bit-identical
    // to the sample-by-sample lerp formula)
    float vmax = -1.f, v2 = -1.f; int dmax = 0;
    #pragma unroll
    for (int k = 0; k < 32; ++k){
        if (DT.f[k] < 0) continue;                 // compile-time dead
        const int d0 = DT.f[k], d1 = DT.l[k];
        const int kh = (k+1 > 31) ? 31 : k+1;
        float Sk = S[k], Sh = S[kh];
        const float w0 = DT.w[d0], w1 = DT.w[d1];
        float vf = Sk*(1.0f-w0) + Sh*w0;
        float vl = Sk*(1.0f-w1) + Sh*w1;
        bool up = vl > vf;
        float segv = up ? vl : vf;
        int   segd = up ? d1 : d0;
        float vr = -1.f;
        if (d1 > d0){
            const float wa = DT.w[d1-1], wb = DT.w[d0+1];
            float va = Sk*(1.0f-wa) + Sh*wa;       // runner if max at last
            float vb = Sk*(1.0f-wb) + Sh*wb;       // runner if max at first
            vr = up ? va : vb;
        }
        if (segv > vmax){ v2 = fmaxf(vmax, vr); vmax = segv; dmax = segd; }
        else            { v2 = fmaxf(v2, segv); }
    }

    float inv  = 1.0f/(sum + 1e-6f);
    float pmax = vmax*inv, p2 = v2*inv;
    float psr  = pmax/(p2 + 1e-6f);
    float cf   = pmax * tanhf(psr);
    cf *= expf(-2.0f*edge[idx]) * fmaxf(1.0f - occ[idx], 0.0f);
    conf[idx]  = cf;
    disp0[idx] = sumd*inv;
    dhk[idx]   = (u32)dmax;
}

// =============== k_nms: 3x3 NMS + edge weights + K count + hi16 hist ===============
__global__ __launch_bounds__(NTH) void k_nms(const float* __restrict__ conf,
        const float* __restrict__ edge, const float* __restrict__ occ,
        u32* __restrict__ dhk, float4* __restrict__ w4pack,
        u32* __restrict__ hist_hi, SelState* st){
    int idx = blockIdx.x*NTH + threadIdx.x;
    int y = idx / WW, x = idx % WW;
    float c = conf[idx];
    float pool = -1e30f;
    #pragma unroll
    for (int dy=-1; dy<=1; ++dy){
        int yy = y+dy; if (yy < 0 || yy >= HH) continue;
        #pragma unroll
        for (int dx=-1; dx<=1; ++dx){
            int xx = x+dx; if (xx < 0 || xx >= WW) continue;
            pool = fmaxf(pool, conf[yy*WW+xx]);
        }
    }
    bool keep = (c >= 0.1f) && (c >= pool);
    dhk[idx] |= keep ? 256u : 0u;

    int yu = min(y+1,HH-1), yd = max(y-1,0), xr = min(x+1,WW-1), xl = max(x-1,0);
    float e  = edge[idx],      o  = occ[idx];
    float e1 = edge[yu*WW+x],  o1 = occ[yu*WW+x];
    float e2 = edge[yd*WW+x],  o2 = occ[yd*WW+x];
    float e3 = edge[y*WW+xr],  o3 = occ[y*WW+xr];
    float e4 = edge[y*WW+xl],  o4 = occ[y*WW+xl];
    float4 wp;
    wp.x = expf(-(e+e1))*(1.f-o)*(1.f-o1);
    wp.y = expf(-(e+e2))*(1.f-o)*(1.f-o2);
    wp.z = expf(-(e+e3))*(1.f-o)*(1.f-o3);
    wp.w = expf(-(e+e4))*(1.f-o)*(1.f-o4);
    w4pack[idx] = wp;

    if (keep) atomicAdd(&hist_hi[__float_as_uint(c) >> 16], 1u);

    u64 m = __ballot(keep);
    __shared__ u32 wc[4];
    int lane = threadIdx.x & 63, wid = threadIdx.x >> 6;
    if (lane == 0) wc[wid] = (u32)__popcll(m);
    __syncthreads();
    if (threadIdx.x == 0) atomicAdd(&st->K, wc[0]+wc[1]+wc[2]+wc[3]);
}

// =============== k_select: fused selection pipeline (grid barriers) ===============
__device__ __forceinline__ void gridbar(u32* cnt, u32 target){
    __syncthreads();
    if (threadIdx.x == 0){
        __threadfence();
        __hip_atomic_fetch_add(cnt, 1u, __ATOMIC_ACQ_REL, __HIP_MEMORY_SCOPE_AGENT);
        while (__hip_atomic_load(cnt, __ATOMIC_ACQUIRE, __HIP_MEMORY_SCOPE_AGENT) < target)
            __builtin_amdgcn_s_sleep(2);
    }
    __syncthreads();
    __threadfence();
}

__global__ __launch_bounds__(NTH, 4) void k_select(const float* __restrict__ conf,
        const float* __restrict__ disp0, u32* __restrict__ dhk,
        float4* __restrict__ w4pack, u32* __restrict__ hist_hi, u32* __restrict__ hist_lo,
        u32* __restrict__ blk_cnt, u32* __restrict__ blk_off,
        SelState* st, u32* __restrict__ barcnt,
        float* __restrict__ nhat, float* __restrict__ Ra){
    __shared__ u32 sh256[256];
    __shared__ u32 wc[4];
    int t = threadIdx.x;
    u32 target = 0;

    // P0: hi16 select (block 0)
    if (blockIdx.x == 0){
        u32 s = 0;
        for (int i = 0; i < 256; ++i) s += hist_hi[t*256 + i];
        sh256[t] = s;
        __syncthreads();
        if (t == 0){
            if (st->K <= TOPK){ st->all_pass = 1; }
            else {
                u32 r = TOPK, suf = 0; int tb = 0;
                for (int u = 255; u >= 0; --u){
                    if (r <= suf + sh256[u]){ tb = u; break; }
                    suf += sh256[u];
                }
                u32 c = suf;
                for (int i = 255; i >= 0; --i){
                    u32 h = hist_hi[tb*256 + i];
                    if (r <= c + h){ st->prefix = (u32)(tb*256 + i); st->r = r - c; break; }
                    c += h;
                }
            }
        }
    }
    gridbar(barcnt, target += SGRID);
    bool ap = (__hip_atomic_load(&st->all_pass, __ATOMIC_ACQUIRE, __HIP_MEMORY_SCOPE_AGENT) != 0);
    u32 prefix = st->prefix;

    // P1: lo16 histogram
    if (!ap){
        for (int cch = blockIdx.x; cch < NCHUNK; cch += SGRID){
            int idx = cch*NTH + t;
            u32 dv = dhk[idx];
            if (dv & 256u){
                u32 key = __float_as_uint(conf[idx]);
                if ((key >> 16) == prefix) atomicAdd(&hist_lo[key & 0xffffu], 1u);
            }
        }
    }
    gridbar(barcnt, target += SGRID);

    // P2: lo16 select (block 0)
    if (blockIdx.x == 0 && !ap){
        u32 s = 0;
        for (int i = 0; i < 256; ++i) s += hist_lo[t*256 + i];
        sh256[t] = s;
        __syncthreads();
        if (t == 0){
            u32 r = st->r, suf = 0; int tb = 0;
            for (int u = 255; u >= 0; --u){
                if (r <= suf + sh256[u]){ tb = u; break; }
                suf += sh256[u];
            }
            u32 c = suf;
            for (int i = 255; i >= 0; --i){
                u32 h = hist_lo[tb*256 + i];
                if (r <= c + h){
                    st->cutoff = (prefix << 16) | (u32)(tb*256 + i);
                    st->n_take = r - c;
                    st->need_rank = ((r - c) != h) ? 1u : 0u;
                    break;
                }
                c += h;
            }
        }
    }
    gridbar(barcnt, target += SGRID);
    u32 cut    = st->cutoff;
    u32 ntake  = st->n_take;
    bool rank  = (!ap) && (__hip_atomic_load(&st->need_rank, __ATOMIC_ACQUIRE, __HIP_MEMORY_SCOPE_AGENT) != 0);

    if (rank){
        // P3: per-chunk eq counts
        for (int cch = blockIdx.x; cch < NCHUNK; cch += SGRID){
            int idx = cch*NTH + t;
            u32 dv = dhk[idx];
            bool flag = (dv & 256u) && (__float_as_uint(conf[idx]) == cut);
            u64 m = __ballot(flag);
            if ((t & 63) == 0) wc[t >> 6] = (u32)__popcll(m);
            __syncthreads();
            if (t == 0) blk_cnt[cch] = wc[0]+wc[1]+wc[2]+wc[3];
            __syncthreads();
        }
        gridbar(barcnt, target += SGRID);
        // P4: scan (block 0)
        if (blockIdx.x == 0){
            u32 v[5]; u32 loc = 0;
            #pragma unroll
            for (int i = 0; i < 5; ++i){
                int j = t*5 + i;
                u32 c = (j < NCHUNK) ? blk_cnt[j] : 0;
                v[i] = loc; loc += c;
            }
            sh256[t] = loc;
            __syncthreads();
            for (int off = 1; off < 256; off <<= 1){
                u32 xval = (t >= off) ? sh256[t-off] : 0;
                __syncthreads();
                sh256[t] += xval;
                __syncthreads();
            }
            u32 base = (t > 0) ? sh256[t-1] : 0;
            #pragma unroll
            for (int i = 0; i < 5; ++i){
                int j = t*5 + i;
                if (j < NCHUNK) blk_off[j] = base + v[i];
            }
        }
        gridbar(barcnt, target += SGRID);
    }

    // P5: final selection + nhat/what + Jacobi iter 1
    for (int cch = blockIdx.x; cch < NCHUNK; cch += SGRID){
        int idx = cch*NTH + t;
        u32 dv = dhk[idx];
        bool keep = (dv & 256u) != 0;
        float c = conf[idx];
        u32 key = __float_as_uint(c);
        bool eq = keep && !ap && (key == cut);

        u64 m = __ballot(eq);
        int lane = t & 63, wid = t >> 6;
        if (lane == 0) wc[wid] = (u32)__popcll(m);
        __syncthreads();
        u32 before = (u32)__popcll(m & ((1ull << lane) - 1ull));
        for (int w = 0; w < wid; ++w) before += wc[w];

        bool kf;
        if (!keep) kf = false;
        else if (ap) kf = true;
        else if (key > cut) kf = true;
        else if (eq) kf = rank ? ((blk_off[cch] + before) < ntake) : true;
        else kf = false;

        float mm = kf ? fminf(fmaxf(c, 0.0f), 1.0f) : 0.0f;
        float4 wp = w4pack[idx];
        float wsum = wp.x + wp.y + wp.z + wp.w + 1e-6f;
        float den = mm + 0.8f*wsum + 1e-6f;
        float n0 = mm * ((float)(dv & 255u) - disp0[idx]);
        float nh = n0 / den;
        float sc = 0.8f / den;
        wp.x *= sc; wp.y *= sc; wp.z *= sc; wp.w *= sc;
        w4pack[idx] = wp;
        nhat[idx] = nh;
        Ra[idx] = nh;
        __syncthreads();
    }
}

// =============== k_jac: 8 Jacobi sweeps, coeffs in regs, R in LDS ===============
__global__ __launch_bounds__(NTH) void k_jac(const float* __restrict__ Rin,
        float* __restrict__ Rout, const float4* __restrict__ Wp,
        const float* __restrict__ Nh, const float* __restrict__ disp0,
        float* __restrict__ out, int K, int final_it){
    __shared__ float Rb[2][1024];   // 8 KB
    int bx = blockIdx.x % 48, by = blockIdx.x / 48;
    int ry0 = by*16 - 8, cx0 = bx*16 - 8;
    int tid = threadIdx.x;

    float4 wr[4]; float nn[4];
    int nUp[4], nDn[4], nLf[4], nRt[4];
    bool inimg[4];
    #pragma unroll
    for (int i = 0; i < 4; ++i){
        int p = tid + i*256;
        int r = p >> 5, c = p & 31;
        int gy = ry0 + r, gx = cx0 + c;
        bool im = ((u32)gy < (u32)HH) && ((u32)gx < (u32)WW);
        inimg[i] = im;
        int cgy = min(max(gy,0),HH-1), cgx = min(max(gx,0),WW-1);
        int g = cgy*WW + cgx;
        wr[i] = Wp[g];
        nn[i] = Nh[g];
        Rb[0][p] = Rin[g];
        nUp[i] = (gy > 0)    ? p-32 : p;
        nDn[i] = (gy < HH-1) ? p+32 : p;
        nLf[i] = (gx > 0)    ? p-1  : p;
        nRt[i] = (gx < WW-1) ? p+1  : p;
    }
    __syncthreads();

    int cur = 0;
    for (int ts = 1; ts <= K; ++ts){
        float nv[4];
        #pragma unroll
        for (int i = 0; i < 4; ++i){
            int p = tid + i*256;
            int r = p >> 5, c = p & 31;
            bool cone = (r >= ts) && (r < 32-ts) && (c >= ts) && (c < 32-ts);
            if (cone && inimg[i]){
                nv[i] = nn[i] + wr[i].x*Rb[cur][nUp[i]] + wr[i].y*Rb[cur][nDn[i]]
                              + wr[i].z*Rb[cur][nLf[i]] + wr[i].w*Rb[cur][nRt[i]];
            } else {
                nv[i] = Rb[cur][p];
            }
        }
        #pragma unroll
        for (int i = 0; i < 4; ++i) Rb[cur^1][tid + i*256] = nv[i];
        __syncthreads();
        cur ^= 1;
    }

    #pragma unroll
    for (int i = 0; i < 4; ++i){
        int p = tid + i*256;
        int r = p >> 5, c = p & 31;
        if (r >= 8 && r < 24 && c >= 8 && c < 24){
            int gy = ry0 + r, gx = cx0 + c;
            int g = gy*WW + gx;
            float Rv = Rb[cur][p];
            if (final_it) out[g] = fmaxf(disp0[g] + Rv, 0.0f);
            else Rout[g] = Rv;
        }
    }
}

extern "C" void kernel_launch(void* const* d_in, const int* in_sizes, int n_in,
                              void* d_out, int out_size, void* d_ws, size_t ws_size,
                              hipStream_t stream) {
    const float* P    = (const float*)d_in[0];
    const float* edge = (const float*)d_in[1];
    const float* occ  = (const float*)d_in[2];
    float* out = (float*)d_out;

    float*  conf   = (float*)d_ws;
    float*  disp0  = conf + HW;
    u32*    dhk    = (u32*)(disp0 + HW);
    float4* w4pack = (float4*)(dhk + HW);       // 16B-aligned (offset multiple of HW*4)
    float*  nhat   = (float*)(w4pack + HW);
    float*  Ra     = nhat + HW;
    float*  Rb     = Ra + HW;
    u32*    hist   = (u32*)(Rb + HW);           // hist_hi[65536] + hist_lo[65536]
    u32*    hist_hi = hist;
    u32*    hist_lo = hist + 65536;
    u32*    blk_cnt = hist_lo + 65536;
    u32*    blk_off = blk_cnt + NCHUNK;
    SelState* st   = (SelState*)(blk_off + NCHUNK);
    u32*    barcnt = (u32*)(st + 1);

    dim3 grid(NBLK), block(NTH);
    k_prob<<<grid, block, 0, stream>>>(P, edge, occ, conf, disp0, dhk, hist, barcnt, st);
    k_nms<<<grid, block, 0, stream>>>(conf, edge, occ, dhk, w4pack, hist_hi, st);
    k_select<<<dim3(SGRID), block, 0, stream>>>(conf, disp0, dhk, w4pack, hist_hi, hist_lo,
                                                blk_cnt, blk_off, st, barcnt, nhat, Ra);
    // iterations 2..30 in 4 halo launches: 8+8+8+5
    k_jac<<<grid, block, 0, stream>>>(Ra, Rb, w4pack, nhat, disp0, out, 8, 0);
    k_jac<<<grid, block, 0, stream>>>(Rb, Ra, w4pack, nhat, disp0, out, 8, 0);
    k_jac<<<grid, block, 0, stream>>>(Ra, Rb, w4pack, nhat, disp0, out, 8, 0);
    k_jac<<<grid, block, 0, stream>>>(Rb, Ra, w4pack, nhat, disp0, out, 5, 1);
}

// Round 8
// 138.178 us; speedup vs baseline: 10.9594x; 10.9594x over previous
//
#include <hip/hip_runtime.h>
#include <hip/hip_bf16.h>

typedef unsigned int u32;
typedef unsigned long long u64;

#define HH 384
#define WW 768
#define HW (HH*WW)
#define H4 96
#define W4 192
#define DLR 32
#define DHR 128
#define TOPK 8000
#define NTH 256
#define NBLK (HW/NTH)    // 1152

// k_prob tiling: 4 rows x 64 cols per block
#define PTW 18
#define PTH 3

struct SelState {
    u32 K, all_pass, prefix, r, cutoff, n_take, need_rank;
};

// ---- compile-time D-interp tables (bit-identical weights to runtime formula) ----
struct DTab {
    float A[32];      // sum coefficients:  sum  = sum_k A[k]*S[k]
    float B[32];      // sumd coefficients: sumd = sum_k B[k]*S[k]
    int   f[32];      // first d with lo==k (-1 if none)
    int   l[32];      // last d with lo==k
    float w[128];     // w per sample d
};
constexpr DTab mk_dtab(){
    DTab t{};
    const float CD = (float)(31.0/127.0);
    for (int k = 0; k < 32; ++k){ t.A[k]=0.f; t.B[k]=0.f; t.f[k]=-1; t.l[k]=-1; }
    for (int d = 0; d < 128; ++d){
        float pos = (float)d * CD;
        int lo = (int)pos; if (lo > 31) lo = 31;
        int hi = (lo+1 > 31) ? 31 : lo+1;
        float w = pos - (float)lo;
        t.w[d] = w;
        t.A[lo] += 1.0f - w;            t.A[hi] += w;
        t.B[lo] += (float)d*(1.0f - w); t.B[hi] += (float)d*w;
        if (t.f[lo] < 0) t.f[lo] = d;
        t.l[lo] = d;
    }
    return t;
}
static constexpr DTab DT = mk_dtab();

// =============== k_prob: interp + prob stats + confidence ===============
__global__ __launch_bounds__(NTH) void k_prob(const float* __restrict__ P,
        const float* __restrict__ edge, const float* __restrict__ occ,
        float* __restrict__ conf, float* __restrict__ disp0, u32* __restrict__ dhk,
        u32* __restrict__ hist, SelState* st){
    // fold init: zero histograms + state (consumed by later kernels, stream-ordered)
    int gtid = blockIdx.x*NTH + threadIdx.x;
    if (gtid < 2*65536) hist[gtid] = 0u;
    if (gtid == 0){
        st->K=0; st->all_pass=0; st->prefix=0; st->r=TOPK; st->cutoff=0; st->n_take=0; st->need_rank=0;
    }

    __shared__ float Sl[DLR][PTH][PTW];     // 6912 B
    __shared__ float YL[4][DLR][19];        // 9728 B (pad 19 for banks)

    int bx = blockIdx.x % 12, by = blockIdx.x / 12;
    int X = bx*64, Y = by*4;
    const float CY = (float)(95.0/383.0);
    const float CX = (float)(191.0/767.0);

    float fy0 = (float)Y * CY; int y0min = (int)fy0; if (y0min > H4-1) y0min = H4-1;
    float fx0 = (float)X * CX; int x0min = (int)fx0; if (x0min > W4-1) x0min = W4-1;

    // stage P_lr window (coalesced global, conflict-free LDS)
    for (int e = threadIdx.x; e < DLR*PTH*PTW; e += NTH){
        int dl  = e / (PTH*PTW);
        int rem = e % (PTH*PTW);
        int ry  = rem / PTW;
        int cx  = rem % PTW;
        int gy = min(y0min + ry, H4-1);
        int gx = min(x0min + cx, W4-1);
        ((float*)Sl)[e] = P[dl*(H4*W4) + gy*W4 + gx];
    }
    __syncthreads();

    // shared y-lerp: 4 out-rows x 32 planes x 18 cols
    for (int e = threadIdx.x; e < 4*DLR*18; e += NTH){
        int ly  = e / (DLR*18);
        int rem = e % (DLR*18);
        int dl  = rem / 18;
        int cx  = rem % 18;
        float fy = (float)(Y + ly) * CY;
        int y0 = (int)fy; if (y0 > H4-1) y0 = H4-1;
        int y1 = min(y0+1, H4-1);
        float wy = fy - (float)y0;
        int ry = y0 - y0min, ryb = y1 - y0min;
        YL[ly][dl][cx] = Sl[dl][ry][cx]*(1.0f-wy) + Sl[dl][ryb][cx]*wy;
    }
    __syncthreads();

    int lx = threadIdx.x & 63, ly = threadIdx.x >> 6;
    int x = X + lx, y = Y + ly;
    int idx = y*WW + x;

    float fx = (float)x * CX;
    int x0 = (int)fx; if (x0 > W4-1) x0 = W4-1;
    float wx = fx - (float)x0;
    float omwx = 1.0f - wx;
    int cxl = x0 - x0min;           // 0..16

    float S[DLR];
    #pragma unroll
    for (int k = 0; k < DLR; ++k)
        S[k] = YL[ly][k][cxl]*omwx + YL[ly][k][cxl+1]*wx;

    // sum / sumd via constexpr coefficients, 4 independent chains
    float s0=0.f,s1=0.f,s2=0.f,s3=0.f, u0=0.f,u1=0.f,u2=0.f,u3=0.f;
    #pragma unroll
    for (int k = 0; k < DLR; k += 4){
        s0 = fmaf(DT.A[k  ], S[k  ], s0); u0 = fmaf(DT.B[k  ], S[k  ], u0);
        s1 = fmaf(DT.A[k+1], S[k+1], s1); u1 = fmaf(DT.B[k+1], S[k+1], u1);
        s2 = fmaf(DT.A[k+2], S[k+2], s2); u2 = fmaf(DT.B[k+2], S[k+2], u2);
        s3 = fmaf(DT.A[k+3], S[k+3], s3); u3 = fmaf(DT.B[k+3], S[k+3], u3);
    }
    float sum  = (s0+s1) + (s2+s3);
    float sumd = (u0+u1) + (u2+u3);

    // top-2 + argmax via per-segment monotonicity (candidate values bit-identical
    // to the sample-by-sample lerp formula)
    float vmax = -1.f, v2 = -1.f; int dmax = 0;
    #pragma unroll
    for (int k = 0; k < 32; ++k){
        if (DT.f[k] < 0) continue;                 // compile-time dead
        const int d0 = DT.f[k], d1 = DT.l[k];
        const int kh = (k+1 > 31) ? 31 : k+1;
        float Sk = S[k], Sh = S[kh];
        const float w0 = DT.w[d0], w1 = DT.w[d1];
        float vf = Sk*(1.0f-w0) + Sh*w0;
        float vl = Sk*(1.0f-w1) + Sh*w1;
        bool up = vl > vf;
        float segv = up ? vl : vf;
        int   segd = up ? d1 : d0;
        float vr = -1.f;
        if (d1 > d0){
            const float wa = DT.w[d1-1], wb = DT.w[d0+1];
            float va = Sk*(1.0f-wa) + Sh*wa;       // runner if max at last
            float vb = Sk*(1.0f-wb) + Sh*wb;       // runner if max at first
            vr = up ? va : vb;
        }
        if (segv > vmax){ v2 = fmaxf(vmax, vr); vmax = segv; dmax = segd; }
        else            { v2 = fmaxf(v2, segv); }
    }

    float inv  = 1.0f/(sum + 1e-6f);
    float pmax = vmax*inv, p2 = v2*inv;
    float psr  = pmax/(p2 + 1e-6f);
    float cf   = pmax * tanhf(psr);
    cf *= expf(-2.0f*edge[idx]) * fmaxf(1.0f - occ[idx], 0.0f);
    conf[idx]  = cf;
    disp0[idx] = sumd*inv;
    dhk[idx]   = (u32)dmax;
}

// =============== k_nms: 3x3 NMS + edge weights + K count + hi16 hist ===============
__global__ __launch_bounds__(NTH) void k_nms(const float* __restrict__ conf,
        const float* __restrict__ edge, const float* __restrict__ occ,
        u32* __restrict__ dhk, float4* __restrict__ w4pack,
        u32* __restrict__ hist_hi, SelState* st){
    int idx = blockIdx.x*NTH + threadIdx.x;
    int y = idx / WW, x = idx % WW;
    float c = conf[idx];
    float pool = -1e30f;
    #pragma unroll
    for (int dy=-1; dy<=1; ++dy){
        int yy = y+dy; if (yy < 0 || yy >= HH) continue;
        #pragma unroll
        for (int dx=-1; dx<=1; ++dx){
            int xx = x+dx; if (xx < 0 || xx >= WW) continue;
            pool = fmaxf(pool, conf[yy*WW+xx]);
        }
    }
    bool keep = (c >= 0.1f) && (c >= pool);
    dhk[idx] |= keep ? 256u : 0u;

    int yu = min(y+1,HH-1), yd = max(y-1,0), xr = min(x+1,WW-1), xl = max(x-1,0);
    float e  = edge[idx],      o  = occ[idx];
    float e1 = edge[yu*WW+x],  o1 = occ[yu*WW+x];
    float e2 = edge[yd*WW+x],  o2 = occ[yd*WW+x];
    float e3 = edge[y*WW+xr],  o3 = occ[y*WW+xr];
    float e4 = edge[y*WW+xl],  o4 = occ[y*WW+xl];
    float4 wp;
    wp.x = expf(-(e+e1))*(1.f-o)*(1.f-o1);
    wp.y = expf(-(e+e2))*(1.f-o)*(1.f-o2);
    wp.z = expf(-(e+e3))*(1.f-o)*(1.f-o3);
    wp.w = expf(-(e+e4))*(1.f-o)*(1.f-o4);
    w4pack[idx] = wp;

    if (keep) atomicAdd(&hist_hi[__float_as_uint(c) >> 16], 1u);

    u64 m = __ballot(keep);
    __shared__ u32 wc[4];
    int lane = threadIdx.x & 63, wid = threadIdx.x >> 6;
    if (lane == 0) wc[wid] = (u32)__popcll(m);
    __syncthreads();
    if (threadIdx.x == 0) atomicAdd(&st->K, wc[0]+wc[1]+wc[2]+wc[3]);
}

// ---- hi16 select (1 block) ----
__global__ void k_advhi(const u32* __restrict__ hist, SelState* st){
    __shared__ u32 csum[256];
    int t = threadIdx.x;
    u32 s = 0;
    for (int i = 0; i < 256; ++i) s += hist[t*256 + i];
    csum[t] = s;
    __syncthreads();
    if (t == 0){
        if (st->K <= TOPK){ st->all_pass = 1; }
        else {
            u32 r = TOPK, suf = 0; int tb = 0;
            for (int u = 255; u >= 0; --u){
                if (r <= suf + csum[u]){ tb = u; break; }
                suf += csum[u];
            }
            u32 c = suf;
            for (int i = 255; i >= 0; --i){
                u32 h = hist[tb*256 + i];
                if (r <= c + h){ st->prefix = (u32)(tb*256 + i); st->r = r - c; break; }
                c += h;
            }
        }
    }
}

// ---- lo16 histogram over matching hi bucket ----
__global__ __launch_bounds__(NTH) void k_histlo(const float* __restrict__ conf,
        const u32* __restrict__ dhk, const SelState* st, u32* __restrict__ hist_lo){
    if (st->all_pass) return;
    int idx = blockIdx.x*NTH + threadIdx.x;
    u32 dv = dhk[idx];
    if (dv & 256u){
        u32 key = __float_as_uint(conf[idx]);
        if ((key >> 16) == st->prefix) atomicAdd(&hist_lo[key & 0xffffu], 1u);
    }
}

// ---- lo16 select (1 block) ----
__global__ void k_advlo(const u32* __restrict__ hist, SelState* st){
    __shared__ u32 csum[256];
    int t = threadIdx.x;
    u32 s = 0;
    for (int i = 0; i < 256; ++i) s += hist[t*256 + i];
    csum[t] = s;
    __syncthreads();
    if (t == 0 && !st->all_pass){
        u32 r = st->r, suf = 0; int tb = 0;
        for (int u = 255; u >= 0; --u){
            if (r <= suf + csum[u]){ tb = u; break; }
            suf += csum[u];
        }
        u32 c = suf;
        for (int i = 255; i >= 0; --i){
            u32 h = hist[tb*256 + i];
            if (r <= c + h){
                st->cutoff = (st->prefix << 16) | (u32)(tb*256 + i);
                st->n_take = r - c;
                st->need_rank = ((r - c) != h) ? 1u : 0u;
                break;
            }
            c += h;
        }
    }
}

// ---- per-block count of cutoff-equal anchors (skipped unless tie needs ranking) ----
__global__ __launch_bounds__(NTH) void k_eqcnt(const float* __restrict__ conf,
        const u32* __restrict__ dhk, const SelState* st, u32* __restrict__ blk_cnt){
    if (st->all_pass || !st->need_rank) return;
    int idx = blockIdx.x*NTH + threadIdx.x;
    u32 dv = dhk[idx];
    bool flag = (dv & 256u) && (__float_as_uint(conf[idx]) == st->cutoff);
    u64 m = __ballot(flag);
    __shared__ u32 wc[4];
    if ((threadIdx.x & 63) == 0) wc[threadIdx.x >> 6] = (u32)__popcll(m);
    __syncthreads();
    if (threadIdx.x == 0) blk_cnt[blockIdx.x] = wc[0]+wc[1]+wc[2]+wc[3];
}

// ---- exclusive scan of block counts (1 block) ----
__global__ void k_scan(const u32* __restrict__ blk_cnt, u32* __restrict__ blk_off,
                       const SelState* st){
    if (st->all_pass || !st->need_rank) return;
    __shared__ u32 s[256];
    int t = threadIdx.x;
    u32 v[5]; u32 loc = 0;
    #pragma unroll
    for (int i = 0; i < 5; ++i){
        int j = t*5 + i;
        u32 c = (j < NBLK) ? blk_cnt[j] : 0;
        v[i] = loc; loc += c;
    }
    s[t] = loc;
    __syncthreads();
    for (int off = 1; off < 256; off <<= 1){
        u32 x = (t >= off) ? s[t-off] : 0;
        __syncthreads();
        s[t] += x;
        __syncthreads();
    }
    u32 base = (t > 0) ? s[t-1] : 0;
    #pragma unroll
    for (int i = 0; i < 5; ++i){
        int j = t*5 + i;
        if (j < NBLK) blk_off[j] = base + v[i];
    }
}

// ---- final selection + nhat/what + Jacobi iter #1 ----
__global__ __launch_bounds__(NTH) void k_finalmaps(const float* __restrict__ conf,
        const float* __restrict__ disp0, const u32* __restrict__ dhk,
        const SelState* st, const u32* __restrict__ blk_off,
        float4* __restrict__ w4pack, float* __restrict__ nhat, float* __restrict__ Ra){
    int idx = blockIdx.x*NTH + threadIdx.x;
    u32 dv = dhk[idx];
    bool keep = (dv & 256u) != 0;
    float c = conf[idx];
    u32 key = __float_as_uint(c);
    bool ap = st->all_pass != 0;
    bool rank = (!ap) && (st->need_rank != 0);
    u32 cut = st->cutoff;
    bool eq = keep && !ap && (key == cut);

    u64 m = __ballot(eq);
    __shared__ u32 wc[4];
    int lane = threadIdx.x & 63, wid = threadIdx.x >> 6;
    if (lane == 0) wc[wid] = (u32)__popcll(m);
    __syncthreads();
    u32 before = (u32)__popcll(m & ((1ull << lane) - 1ull));
    for (int w = 0; w < wid; ++w) before += wc[w];

    bool kf;
    if (!keep) kf = false;
    else if (ap) kf = true;
    else if (key > cut) kf = true;
    else if (eq) kf = rank ? ((blk_off[blockIdx.x] + before) < st->n_take) : true;
    else kf = false;

    float mm = kf ? fminf(fmaxf(c, 0.0f), 1.0f) : 0.0f;
    float4 wp = w4pack[idx];
    float wsum = wp.x + wp.y + wp.z + wp.w + 1e-6f;
    float den = mm + 0.8f*wsum + 1e-6f;
    float n0 = mm * ((float)(dv & 255u) - disp0[idx]);
    float nh = n0 / den;
    float sc = 0.8f / den;
    wp.x *= sc; wp.y *= sc; wp.z *= sc; wp.w *= sc;
    w4pack[idx] = wp;
    nhat[idx] = nh;
    Ra[idx] = nh;   // iteration 1 (R_prev = 0)
}

// =============== k_jac: K Jacobi sweeps, coeffs in regs, R in LDS ===============
__global__ __launch_bounds__(NTH) void k_jac(const float* __restrict__ Rin,
        float* __restrict__ Rout, const float4* __restrict__ Wp,
        const float* __restrict__ Nh, const float* __restrict__ disp0,
        float* __restrict__ out, int K, int final_it){
    __shared__ float Rb[2][1024];   // 8 KB
    int bx = blockIdx.x % 48, by = blockIdx.x / 48;
    int ry0 = by*16 - 8, cx0 = bx*16 - 8;
    int tid = threadIdx.x;

    float4 wr[4]; float nn[4];
    int nUp[4], nDn[4], nLf[4], nRt[4];
    bool inimg[4];
    #pragma unroll
    for (int i = 0; i < 4; ++i){
        int p = tid + i*256;
        int r = p >> 5, c = p & 31;
        int gy = ry0 + r, gx = cx0 + c;
        bool im = ((u32)gy < (u32)HH) && ((u32)gx < (u32)WW);
        inimg[i] = im;
        int cgy = min(max(gy,0),HH-1), cgx = min(max(gx,0),WW-1);
        int g = cgy*WW + cgx;
        wr[i] = Wp[g];
        nn[i] = Nh[g];
        Rb[0][p] = Rin[g];
        nUp[i] = (gy > 0)    ? p-32 : p;
        nDn[i] = (gy < HH-1) ? p+32 : p;
        nLf[i] = (gx > 0)    ? p-1  : p;
        nRt[i] = (gx < WW-1) ? p+1  : p;
    }
    __syncthreads();

    int cur = 0;
    for (int ts = 1; ts <= K; ++ts){
        float nv[4];
        #pragma unroll
        for (int i = 0; i < 4; ++i){
            int p = tid + i*256;
            int r = p >> 5, c = p & 31;
            bool cone = (r >= ts) && (r < 32-ts) && (c >= ts) && (c < 32-ts);
            if (cone && inimg[i]){
                nv[i] = nn[i] + wr[i].x*Rb[cur][nUp[i]] + wr[i].y*Rb[cur][nDn[i]]
                              + wr[i].z*Rb[cur][nLf[i]] + wr[i].w*Rb[cur][nRt[i]];
            } else {
                nv[i] = Rb[cur][p];
            }
        }
        #pragma unroll
        for (int i = 0; i < 4; ++i) Rb[cur^1][tid + i*256] = nv[i];
        __syncthreads();
        cur ^= 1;
    }

    #pragma unroll
    for (int i = 0; i < 4; ++i){
        int p = tid + i*256;
        int r = p >> 5, c = p & 31;
        if (r >= 8 && r < 24 && c >= 8 && c < 24){
            int gy = ry0 + r, gx = cx0 + c;
            int g = gy*WW + gx;
            float Rv = Rb[cur][p];
            if (final_it) out[g] = fmaxf(disp0[g] + Rv, 0.0f);
            else Rout[g] = Rv;
        }
    }
}

extern "C" void kernel_launch(void* const* d_in, const int* in_sizes, int n_in,
                              void* d_out, int out_size, void* d_ws, size_t ws_size,
                              hipStream_t stream) {
    const float* P    = (const float*)d_in[0];
    const float* edge = (const float*)d_in[1];
    const float* occ  = (const float*)d_in[2];
    float* out = (float*)d_out;

    float*  conf   = (float*)d_ws;
    float*  disp0  = conf + HW;
    u32*    dhk    = (u32*)(disp0 + HW);
    float4* w4pack = (float4*)(dhk + HW);       // 16B-aligned (offset multiple of HW*4)
    float*  nhat   = (float*)(w4pack + HW);
    float*  Ra     = nhat + HW;
    float*  Rb     = Ra + HW;
    u32*    hist   = (u32*)(Rb + HW);           // hist_hi[65536] + hist_lo[65536]
    u32*    hist_hi = hist;
    u32*    hist_lo = hist + 65536;
    u32*    blk_cnt = hist_lo + 65536;
    u32*    blk_off = blk_cnt + NBLK;
    SelState* st   = (SelState*)(blk_off + NBLK);

    dim3 grid(NBLK), block(NTH);
    k_prob<<<grid, block, 0, stream>>>(P, edge, occ, conf, disp0, dhk, hist, st);
    k_nms<<<grid, block, 0, stream>>>(conf, edge, occ, dhk, w4pack, hist_hi, st);
    k_advhi<<<1, 256, 0, stream>>>(hist_hi, st);
    k_histlo<<<grid, block, 0, stream>>>(conf, dhk, st, hist_lo);
    k_advlo<<<1, 256, 0, stream>>>(hist_lo, st);
    k_eqcnt<<<grid, block, 0, stream>>>(conf, dhk, st, blk_cnt);
    k_scan<<<1, 256, 0, stream>>>(blk_cnt, blk_off, st);
    k_finalmaps<<<grid, block, 0, stream>>>(conf, disp0, dhk, st, blk_off,
                                            w4pack, nhat, Ra);
    // iterations 2..30 in 4 halo launches: 8+8+8+5
    k_jac<<<grid, block, 0, stream>>>(Ra, Rb, w4pack, nhat, disp0, out, 8, 0);
    k_jac<<<grid, block, 0, stream>>>(Rb, Ra, w4pack, nhat, disp0, out, 8, 0);
    k_jac<<<grid, block, 0, stream>>>(Ra, Rb, w4pack, nhat, disp0, out, 8, 0);
    k_jac<<<grid, block, 0, stream>>>(Rb, Ra, w4pack, nhat, disp0, out, 5, 1);
}